// Round 7
// baseline (133.581 us; speedup 1.0000x reference)
//
#include <hip/hip_runtime.h>
#include <math.h>

typedef float f4 __attribute__((ext_vector_type(4)));
typedef int   i2 __attribute__((ext_vector_type(2)));

#define NCg 128
#define NAg 65
#define KNUM 128
#define PDIM 64
#define EDIM 256
#define NEDGE (NCg*NAg*NAg)      // 540800
#define NROWS (NCg*NAg)          // 8320
#define TLO -8.0f
#define TSPAN 144                // xs domain [-8,136]; clamped outside
#define TPTS 4                   // table grid points per block

// ---------------------------------------------------------------------------
// Kernel A: build g_d(xs) table.  (round-4 version — verified fast)
// ---------------------------------------------------------------------------
__launch_bounds__(128)
__global__ void table_kernel(const float* __restrict__ mean,
                             const float* __restrict__ w1,
                             const float* __restrict__ b1,
                             const float* __restrict__ w2,
                             const float* __restrict__ b2,
                             float* __restrict__ T,
                             float invres, int npt)
{
    __shared__ f4 wbuf[128*17];          // 34.8KB; w1 half [128 rows][16+1 f4]
                                         // reused for w2 as [64 rows][32+1 f4]
    __shared__ f4 gb4[KNUM];
    __shared__ f4 h4[KNUM];

    const int t  = threadIdx.x;          // 128 threads
    const int p0 = blockIdx.x * TPTS;

    const float stdv     = mean[1] - mean[0];
    const float inv_astd = 1.0f / (sqrtf(6.28318f) * stdv);

    {
        f4 g;
        float u0 = TLO + (float)(p0+0)*invres - (float)t;
        float u1 = TLO + (float)(p0+1)*invres - (float)t;
        float u2 = TLO + (float)(p0+2)*invres - (float)t;
        float u3 = TLO + (float)(p0+3)*invres - (float)t;
        g.x = expf(-0.5f*u0*u0) * inv_astd;
        g.y = expf(-0.5f*u1*u1) * inv_astd;
        g.z = expf(-0.5f*u2*u2) * inv_astd;
        g.w = expf(-0.5f*u3*u3) * inv_astd;
        gb4[t] = g;
    }

    f4 acc = {0.f, 0.f, 0.f, 0.f};
    for (int H = 0; H < 2; ++H) {
        __syncthreads();
        for (int it = 0; it < 16; ++it) {
            int u   = t + 128*it;
            int row = u >> 4;
            int c4  = u & 15;
            wbuf[row*17 + c4] = ((const f4*)w1)[row*32 + H*16 + c4];
        }
        __syncthreads();
        const f4* wr = &wbuf[t*17];
        #pragma unroll
        for (int kq = 0; kq < 16; ++kq) {
            f4 wv = wr[kq];
            int kb = H*64 + kq*4;
            acc = acc + wv.x * gb4[kb+0];
            acc = acc + wv.y * gb4[kb+1];
            acc = acc + wv.z * gb4[kb+2];
            acc = acc + wv.w * gb4[kb+3];
        }
    }
    {
        float b1t = b1[t];
        f4 hv;
        hv.x = 0.5f*acc.x*(1.0f + erff(acc.x*0.70710678118654752f)) + b1t;
        hv.y = 0.5f*acc.y*(1.0f + erff(acc.y*0.70710678118654752f)) + b1t;
        hv.z = 0.5f*acc.z*(1.0f + erff(acc.z*0.70710678118654752f)) + b1t;
        hv.w = 0.5f*acc.w*(1.0f + erff(acc.w*0.70710678118654752f)) + b1t;
        h4[t] = hv;
    }
    __syncthreads();
    for (int it = 0; it < 16; ++it) {
        int u   = t + 128*it;
        int row = u >> 5;
        int c4  = u & 31;
        wbuf[row*33 + c4] = ((const f4*)w2)[u];
    }
    __syncthreads();

    if (t < PDIM) {
        float b2t = b2[t];
        f4 o = {b2t, b2t, b2t, b2t};
        const f4* wr = &wbuf[t*33];
        #pragma unroll
        for (int kq = 0; kq < 32; ++kq) {
            f4 wv = wr[kq];
            o = o + wv.x * h4[kq*4+0];
            o = o + wv.y * h4[kq*4+1];
            o = o + wv.z * h4[kq*4+2];
            o = o + wv.w * h4[kq*4+3];
        }
        if (p0+0 < npt) T[(size_t)(p0+0)*PDIM + t] = o.x;
        if (p0+1 < npt) T[(size_t)(p0+1)*PDIM + t] = o.y;
        if (p0+2 < npt) T[(size_t)(p0+2)*PDIM + t] = o.z;
        if (p0+3 < npt) T[(size_t)(p0+3)*PDIM + t] = o.w;
    }
}

// ---------------------------------------------------------------------------
// Kernel B: atom path.  16 rows/block; meta inline; nt stores.
// EXACT round-4 form (measured inside the 120.8us total).  The round-5/6
// "register-tile + LDS-transposed-ep_w" restructure REGRESSED (+~10us
// suspected): LDS 12.3->45.6KB cut occupancy 8->3 blocks/CU, added 8
// barriers and 32K bank-conflicted scalar ds_writes.  The 512B-stride ep_w
// reads here are fine in practice: each wv4 register is reused x16 (rr
// unroll) and ep_w (128KB) is L2-resident across all 520 blocks.
// ---------------------------------------------------------------------------
__launch_bounds__(256)
__global__ void atom_kernel(const float* __restrict__ coord,
                            const float* __restrict__ atom_feat,
                            const int*   __restrict__ etype,
                            const float* __restrict__ mul_w,
                            const float* __restrict__ bias_w,
                            const float* __restrict__ mean,
                            const float* __restrict__ ep_w,
                            const float* __restrict__ ep_b,
                            float* __restrict__ out_atom)
{
    __shared__ float x_s[16*NAg];
    __shared__ float sum_s[16*KNUM];

    const int t  = threadIdx.x;
    const int r0 = blockIdx.x * 16;

    const float stdv     = mean[1] - mean[0];
    const float inv_std  = 1.0f / stdv;
    const float inv_astd = 1.0f / (sqrtf(6.28318f) * stdv);

    for (int it = 0; it < 5; ++it) {
        int item = t + 256*it;
        if (item < 16*NAg) {
            int rr = item / NAg;
            int j  = item - rr*NAg;
            int r  = r0 + rr;
            int c  = r / NAg;
            int i  = r - c*NAg;
            const float* ci = coord + (c*NAg + i)*3;
            const float* cj = coord + (c*NAg + j)*3;
            float dx = cj[0]-ci[0], dy = cj[1]-ci[1], dz = cj[2]-ci[2];
            float dist = sqrtf(dx*dx + dy*dy + dz*dz);
            int t0 = etype[(r*NAg+j)*2+0], t1 = etype[(r*NAg+j)*2+1];
            float mul  = fabsf(mul_w[t0]) + fabsf(mul_w[t1]);
            float bias = bias_w[t0] + bias_w[t1];
            x_s[item] = (mul*dist + bias) * inv_std;
        }
    }
    __syncthreads();

    for (int it = 0; it < 8; ++it) {
        int item = t + 256*it;              // 16*128 = 2048
        int rr = item >> 7;
        int k  = item & 127;
        float fk = (float)k;
        const float* xr = &x_s[rr*NAg];
        float a0=0.f, a1=0.f, a2=0.f, a3=0.f;
        int j = 0;
        for (; j <= NAg-4; j += 4) {
            float u0 = xr[j+0]-fk, u1 = xr[j+1]-fk, u2 = xr[j+2]-fk, u3 = xr[j+3]-fk;
            a0 += exp2f(u0*u0 * -0.72134752f);
            a1 += exp2f(u1*u1 * -0.72134752f);
            a2 += exp2f(u2*u2 * -0.72134752f);
            a3 += exp2f(u3*u3 * -0.72134752f);
        }
        for (; j < NAg; ++j) {
            float u0 = xr[j]-fk;
            a0 += exp2f(u0*u0 * -0.72134752f);
        }
        sum_s[item] = ((a0+a1)+(a2+a3)) * inv_astd;
    }
    __syncthreads();

    {
        const int d = t;                    // 0..255
        float acc[16] = {};
        for (int kk = 0; kk < 32; ++kk) {
            f4 wv4 = *(const f4*)&ep_w[d*KNUM + 4*kk];
            #pragma unroll
            for (int rr = 0; rr < 16; ++rr) {
                f4 sv = *(const f4*)&sum_s[rr*KNUM + 4*kk];
                acc[rr] = fmaf(sv.x, wv4.x,
                          fmaf(sv.y, wv4.y,
                          fmaf(sv.z, wv4.z,
                          fmaf(sv.w, wv4.w, acc[rr]))));
            }
        }
        float epb = ep_b[d];
        #pragma unroll
        for (int rr = 0; rr < 16; ++rr) {
            int o = (r0 + rr)*EDIM + d;
            float af = __builtin_nontemporal_load(&atom_feat[o]);
            __builtin_nontemporal_store(af + acc[rr] + epb, &out_atom[o]);
        }
    }
}

// ---------------------------------------------------------------------------
// Kernel C: attn stream + delta.  Block = 128 edges, barrier-free main path.
// Keeps round-6's nt ef/etype loads (A/B test: atom reverted, nt kept).
// ---------------------------------------------------------------------------
__launch_bounds__(256)
__global__ void attn_kernel(const float* __restrict__ coord,
                            const int*   __restrict__ etype,
                            const float* __restrict__ mul_w,
                            const float* __restrict__ bias_w,
                            const float* __restrict__ mean,
                            const float* __restrict__ edge_feat,
                            const float* __restrict__ T,
                            float fres, int npt,
                            float* __restrict__ out_attn,
                            float* __restrict__ out_delta)
{
    __shared__ __attribute__((aligned(16))) float dl[128*3];

    const int t  = threadIdx.x;
    const int dq = t & 15;
    const int er = t >> 4;                        // 0..15
    const size_t u0 = (size_t)blockIdx.x * 2048;  // f4 units
    const int e0 = blockIdx.x * 128;

    const float inv_std = 1.0f / (mean[1] - mean[0]);

    // ---- edge_feature loads first: longest-latency, fully independent ----
    f4 ef[8];
    #pragma unroll
    for (int p = 0; p < 8; ++p)
        ef[p] = __builtin_nontemporal_load((const f4*)edge_feat + u0 + p*256 + t);

    // ---- inline meta -> xs (16-lane redundant, no barrier), delta to LDS --
    float xsv[8];
    #pragma unroll
    for (int p = 0; p < 8; ++p) {
        int eg  = e0 + p*16 + er;
        int c   = eg / (NAg*NAg);
        int rem = eg - c*(NAg*NAg);
        int i   = rem / NAg;
        int j   = rem - i*NAg;
        const float* ci = coord + (c*NAg + i)*3;
        const float* cj = coord + (c*NAg + j)*3;
        float dx = cj[0]-ci[0], dy = cj[1]-ci[1], dz = cj[2]-ci[2];
        if (dq < 3) dl[(p*16+er)*3 + dq] = (dq==0) ? dx : ((dq==1) ? dy : dz);
        float dist = sqrtf(dx*dx + dy*dy + dz*dz);
        i2 tp = __builtin_nontemporal_load((const i2*)&etype[(size_t)eg*2]);
        float mul  = fabsf(mul_w[tp.x]) + fabsf(mul_w[tp.y]);
        float bias = bias_w[tp.x] + bias_w[tp.y];
        xsv[p] = (mul*dist + bias) * inv_std;
    }

    int idx[8]; float fr[8];
    #pragma unroll
    for (int p = 0; p < 8; ++p) {
        float ti = (xsv[p] - TLO) * fres;
        int   i  = (int)ti;
        i = i < 0 ? 0 : (i > npt-2 ? npt-2 : i);
        float f = ti - (float)i;
        fr[p]  = f < 0.0f ? 0.0f : (f > 1.0f ? 1.0f : f);
        idx[p] = i;
    }

    // ---- per 4-edge group: gather + lerp + add + nt store ----
    #pragma unroll
    for (int g = 0; g < 2; ++g) {
        f4 lo[4], hi[4];
        #pragma unroll
        for (int q = 0; q < 4; ++q) {
            int p = g*4 + q;
            const float* tr = T + (size_t)idx[p]*PDIM + dq*4;
            lo[q] = *(const f4*)tr;
            hi[q] = *(const f4*)(tr + PDIM);
        }
        #pragma unroll
        for (int q = 0; q < 4; ++q) {
            int p = g*4 + q;
            f4 o;
            o.x = fmaf(fr[p], hi[q].x - lo[q].x, lo[q].x) + ef[p].x;
            o.y = fmaf(fr[p], hi[q].y - lo[q].y, lo[q].y) + ef[p].y;
            o.z = fmaf(fr[p], hi[q].z - lo[q].z, lo[q].z) + ef[p].z;
            o.w = fmaf(fr[p], hi[q].w - lo[q].w, lo[q].w) + ef[p].w;
            __builtin_nontemporal_store(o, (f4*)out_attn + u0 + p*256 + t);
        }
    }

    // ---- delta_pos: 384 floats = 96 coalesced f4 nt stores ----
    __syncthreads();
    if (t < 96) {
        f4 dv = *(const f4*)&dl[t*4];
        __builtin_nontemporal_store(dv, (f4*)(out_delta) + (size_t)blockIdx.x*96 + t);
    }
}

extern "C" void kernel_launch(void* const* d_in, const int* in_sizes, int n_in,
                              void* d_out, int out_size, void* d_ws, size_t ws_size,
                              hipStream_t stream) {
    const float* coord     = (const float*)d_in[0];
    const float* atom_feat = (const float*)d_in[1];
    const int*   etype     = (const int*)  d_in[2];
    const float* edge_feat = (const float*)d_in[3];
    const float* mul_w     = (const float*)d_in[4];
    const float* bias_w    = (const float*)d_in[5];
    const float* mean      = (const float*)d_in[6];
    const float* w1        = (const float*)d_in[7];
    const float* b1        = (const float*)d_in[8];
    const float* w2        = (const float*)d_in[9];
    const float* b2        = (const float*)d_in[10];
    const float* ep_w      = (const float*)d_in[11];
    const float* ep_b      = (const float*)d_in[12];

    float* out = (float*)d_out;
    float* out_atom  = out;
    float* out_attn  = out + (size_t)NCg*NAg*EDIM;
    float* out_delta = out + (size_t)NCg*NAg*EDIM + (size_t)NEDGE*PDIM;

    auto tblBytes = [](int res){ return (size_t)(TSPAN*res+1)*PDIM*4; };
    int res;
    if      (ws_size >= tblBytes(16)) res = 16;   // 590 KB
    else if (ws_size >= tblBytes(4))  res = 4;
    else                              res = 1;
    int npt = TSPAN*res + 1;
    float* Tbl = (float*)d_ws;

    table_kernel<<<(npt + TPTS - 1)/TPTS, 128, 0, stream>>>(
        mean, w1, b1, w2, b2, Tbl, 1.0f/(float)res, npt);

    atom_kernel<<<NROWS/16, 256, 0, stream>>>(
        coord, atom_feat, etype, mul_w, bias_w, mean, ep_w, ep_b, out_atom);

    attn_kernel<<<NEDGE/128, 256, 0, stream>>>(
        coord, etype, mul_w, bias_w, mean, edge_feat, Tbl,
        (float)res, npt, out_attn, out_delta);
}

// Round 8
// 92.346 us; speedup vs baseline: 1.4465x; 1.4465x over previous
//
#include <hip/hip_runtime.h>
#include <math.h>

typedef float f4 __attribute__((ext_vector_type(4)));

#define NCg 128
#define NAg 65
#define KNUM 128
#define PDIM 64
#define EDIM 256
#define NEDGE (NCg*NAg*NAg)      // 540800
#define NROWS (NCg*NAg)          // 8320
#define NATOMBLK (NROWS/16)      // 520 atom blocks
#define NATTNBLK (NEDGE/128)     // 4225 attn blocks
#define TLO -8.0f
#define TSPAN 144                // xs domain [-8,136]; clamped outside
#define TPTS 4                   // table grid points per block

// ---------------------------------------------------------------------------
// Kernel A: build g_d(xs) table.  (round-4 version — verified fast)
// ---------------------------------------------------------------------------
__launch_bounds__(128)
__global__ void table_kernel(const float* __restrict__ mean,
                             const float* __restrict__ w1,
                             const float* __restrict__ b1,
                             const float* __restrict__ w2,
                             const float* __restrict__ b2,
                             float* __restrict__ T,
                             float invres, int npt)
{
    __shared__ f4 wbuf[128*17];          // 34.8KB; w1 half [128 rows][16+1 f4]
                                         // reused for w2 as [64 rows][32+1 f4]
    __shared__ f4 gb4[KNUM];
    __shared__ f4 h4[KNUM];

    const int t  = threadIdx.x;          // 128 threads
    const int p0 = blockIdx.x * TPTS;

    const float stdv     = mean[1] - mean[0];
    const float inv_astd = 1.0f / (sqrtf(6.28318f) * stdv);

    {
        f4 g;
        float u0 = TLO + (float)(p0+0)*invres - (float)t;
        float u1 = TLO + (float)(p0+1)*invres - (float)t;
        float u2 = TLO + (float)(p0+2)*invres - (float)t;
        float u3 = TLO + (float)(p0+3)*invres - (float)t;
        g.x = expf(-0.5f*u0*u0) * inv_astd;
        g.y = expf(-0.5f*u1*u1) * inv_astd;
        g.z = expf(-0.5f*u2*u2) * inv_astd;
        g.w = expf(-0.5f*u3*u3) * inv_astd;
        gb4[t] = g;
    }

    f4 acc = {0.f, 0.f, 0.f, 0.f};
    for (int H = 0; H < 2; ++H) {
        __syncthreads();
        for (int it = 0; it < 16; ++it) {
            int u   = t + 128*it;
            int row = u >> 4;
            int c4  = u & 15;
            wbuf[row*17 + c4] = ((const f4*)w1)[row*32 + H*16 + c4];
        }
        __syncthreads();
        const f4* wr = &wbuf[t*17];
        #pragma unroll
        for (int kq = 0; kq < 16; ++kq) {
            f4 wv = wr[kq];
            int kb = H*64 + kq*4;
            acc = acc + wv.x * gb4[kb+0];
            acc = acc + wv.y * gb4[kb+1];
            acc = acc + wv.z * gb4[kb+2];
            acc = acc + wv.w * gb4[kb+3];
        }
    }
    {
        float b1t = b1[t];
        f4 hv;
        hv.x = 0.5f*acc.x*(1.0f + erff(acc.x*0.70710678118654752f)) + b1t;
        hv.y = 0.5f*acc.y*(1.0f + erff(acc.y*0.70710678118654752f)) + b1t;
        hv.z = 0.5f*acc.z*(1.0f + erff(acc.z*0.70710678118654752f)) + b1t;
        hv.w = 0.5f*acc.w*(1.0f + erff(acc.w*0.70710678118654752f)) + b1t;
        h4[t] = hv;
    }
    __syncthreads();
    for (int it = 0; it < 16; ++it) {
        int u   = t + 128*it;
        int row = u >> 5;
        int c4  = u & 31;
        wbuf[row*33 + c4] = ((const f4*)w2)[u];
    }
    __syncthreads();

    if (t < PDIM) {
        float b2t = b2[t];
        f4 o = {b2t, b2t, b2t, b2t};
        const f4* wr = &wbuf[t*33];
        #pragma unroll
        for (int kq = 0; kq < 32; ++kq) {
            f4 wv = wr[kq];
            o = o + wv.x * h4[kq*4+0];
            o = o + wv.y * h4[kq*4+1];
            o = o + wv.z * h4[kq*4+2];
            o = o + wv.w * h4[kq*4+3];
        }
        if (p0+0 < npt) T[(size_t)(p0+0)*PDIM + t] = o.x;
        if (p0+1 < npt) T[(size_t)(p0+1)*PDIM + t] = o.y;
        if (p0+2 < npt) T[(size_t)(p0+2)*PDIM + t] = o.z;
        if (p0+3 < npt) T[(size_t)(p0+3)*PDIM + t] = o.w;
    }
}

// ---------------------------------------------------------------------------
// Fused kernel: blocks [0, NATOMBLK) run the atom path (round-4 form),
// blocks [NATOMBLK, NATOMBLK+NATTNBLK) run the attn path (round-4 form,
// CACHED ef/etype loads — the r5/r6 nt loads cost +12us, measured A/B).
// atom has no dependency on T and disjoint outputs -> fusion is safe; atom
// blocks dispatch first and hide entirely under the attn stream.
// LDS is a union: atom needs 12.3KB, attn 1.5KB.
// ---------------------------------------------------------------------------
__launch_bounds__(256)
__global__ void fused_kernel(const float* __restrict__ coord,
                             const float* __restrict__ atom_feat,
                             const int*   __restrict__ etype,
                             const float* __restrict__ mul_w,
                             const float* __restrict__ bias_w,
                             const float* __restrict__ mean,
                             const float* __restrict__ ep_w,
                             const float* __restrict__ ep_b,
                             const float* __restrict__ edge_feat,
                             const float* __restrict__ T,
                             float fres, int npt,
                             float* __restrict__ out_atom,
                             float* __restrict__ out_attn,
                             float* __restrict__ out_delta)
{
    __shared__ __attribute__((aligned(16))) float smem[16*NAg + 16*KNUM];

    const int t = threadIdx.x;
    const float stdv    = mean[1] - mean[0];
    const float inv_std = 1.0f / stdv;

    if (blockIdx.x < NATOMBLK) {
        // =================== atom path (exact round-4 body) ===================
        float* x_s   = smem;               // [16*NAg]
        float* sum_s = smem + 16*NAg;      // [16*KNUM]
        const int r0 = blockIdx.x * 16;
        const float inv_astd = 1.0f / (sqrtf(6.28318f) * stdv);

        for (int it = 0; it < 5; ++it) {
            int item = t + 256*it;
            if (item < 16*NAg) {
                int rr = item / NAg;
                int j  = item - rr*NAg;
                int r  = r0 + rr;
                int c  = r / NAg;
                int i  = r - c*NAg;
                const float* ci = coord + (c*NAg + i)*3;
                const float* cj = coord + (c*NAg + j)*3;
                float dx = cj[0]-ci[0], dy = cj[1]-ci[1], dz = cj[2]-ci[2];
                float dist = sqrtf(dx*dx + dy*dy + dz*dz);
                int t0 = etype[(r*NAg+j)*2+0], t1 = etype[(r*NAg+j)*2+1];
                float mul  = fabsf(mul_w[t0]) + fabsf(mul_w[t1]);
                float bias = bias_w[t0] + bias_w[t1];
                x_s[item] = (mul*dist + bias) * inv_std;
            }
        }
        __syncthreads();

        for (int it = 0; it < 8; ++it) {
            int item = t + 256*it;              // 16*128 = 2048
            int rr = item >> 7;
            int k  = item & 127;
            float fk = (float)k;
            const float* xr = &x_s[rr*NAg];
            float a0=0.f, a1=0.f, a2=0.f, a3=0.f;
            int j = 0;
            for (; j <= NAg-4; j += 4) {
                float u0 = xr[j+0]-fk, u1 = xr[j+1]-fk, u2 = xr[j+2]-fk, u3 = xr[j+3]-fk;
                a0 += exp2f(u0*u0 * -0.72134752f);
                a1 += exp2f(u1*u1 * -0.72134752f);
                a2 += exp2f(u2*u2 * -0.72134752f);
                a3 += exp2f(u3*u3 * -0.72134752f);
            }
            for (; j < NAg; ++j) {
                float u0 = xr[j]-fk;
                a0 += exp2f(u0*u0 * -0.72134752f);
            }
            sum_s[item] = ((a0+a1)+(a2+a3)) * inv_astd;
        }
        __syncthreads();

        {
            const int d = t;                    // 0..255
            float acc[16] = {};
            for (int kk = 0; kk < 32; ++kk) {
                f4 wv4 = *(const f4*)&ep_w[d*KNUM + 4*kk];
                #pragma unroll
                for (int rr = 0; rr < 16; ++rr) {
                    f4 sv = *(const f4*)&sum_s[rr*KNUM + 4*kk];
                    acc[rr] = fmaf(sv.x, wv4.x,
                              fmaf(sv.y, wv4.y,
                              fmaf(sv.z, wv4.z,
                              fmaf(sv.w, wv4.w, acc[rr]))));
                }
            }
            float epb = ep_b[d];
            #pragma unroll
            for (int rr = 0; rr < 16; ++rr) {
                int o = (r0 + rr)*EDIM + d;
                float af = __builtin_nontemporal_load(&atom_feat[o]);
                __builtin_nontemporal_store(af + acc[rr] + epb, &out_atom[o]);
            }
        }
    } else {
        // =================== attn path (exact round-4 body) ===================
        float* dl = smem;                   // [128*3], 16B-aligned
        const int bid = blockIdx.x - NATOMBLK;
        const int dq = t & 15;
        const int er = t >> 4;                        // 0..15
        const size_t u0 = (size_t)bid * 2048;         // f4 units
        const int e0 = bid * 128;

        // ---- edge_feature loads first: longest-latency, fully independent --
        f4 ef[8];
        #pragma unroll
        for (int p = 0; p < 8; ++p)
            ef[p] = ((const f4*)edge_feat)[u0 + p*256 + t];

        // ---- inline meta -> xs (16-lane redundant, no barrier) ----
        float xsv[8];
        #pragma unroll
        for (int p = 0; p < 8; ++p) {
            int eg  = e0 + p*16 + er;
            int c   = eg / (NAg*NAg);
            int rem = eg - c*(NAg*NAg);
            int i   = rem / NAg;
            int j   = rem - i*NAg;
            const float* ci = coord + (c*NAg + i)*3;
            const float* cj = coord + (c*NAg + j)*3;
            float dx = cj[0]-ci[0], dy = cj[1]-ci[1], dz = cj[2]-ci[2];
            if (dq < 3) dl[(p*16+er)*3 + dq] = (dq==0) ? dx : ((dq==1) ? dy : dz);
            float dist = sqrtf(dx*dx + dy*dy + dz*dz);
            int2 tp = *(const int2*)&etype[(size_t)eg*2];
            float mul  = fabsf(mul_w[tp.x]) + fabsf(mul_w[tp.y]);
            float bias = bias_w[tp.x] + bias_w[tp.y];
            xsv[p] = (mul*dist + bias) * inv_std;
        }

        int idx[8]; float fr[8];
        #pragma unroll
        for (int p = 0; p < 8; ++p) {
            float ti = (xsv[p] - TLO) * fres;
            int   i  = (int)ti;
            i = i < 0 ? 0 : (i > npt-2 ? npt-2 : i);
            float f = ti - (float)i;
            fr[p]  = f < 0.0f ? 0.0f : (f > 1.0f ? 1.0f : f);
            idx[p] = i;
        }

        // ---- per 4-edge group: gather + lerp + add + nt store ----
        #pragma unroll
        for (int g = 0; g < 2; ++g) {
            f4 lo[4], hi[4];
            #pragma unroll
            for (int q = 0; q < 4; ++q) {
                int p = g*4 + q;
                const float* tr = T + (size_t)idx[p]*PDIM + dq*4;
                lo[q] = *(const f4*)tr;
                hi[q] = *(const f4*)(tr + PDIM);
            }
            #pragma unroll
            for (int q = 0; q < 4; ++q) {
                int p = g*4 + q;
                f4 o;
                o.x = fmaf(fr[p], hi[q].x - lo[q].x, lo[q].x) + ef[p].x;
                o.y = fmaf(fr[p], hi[q].y - lo[q].y, lo[q].y) + ef[p].y;
                o.z = fmaf(fr[p], hi[q].z - lo[q].z, lo[q].z) + ef[p].z;
                o.w = fmaf(fr[p], hi[q].w - lo[q].w, lo[q].w) + ef[p].w;
                __builtin_nontemporal_store(o, (f4*)out_attn + u0 + p*256 + t);
            }
        }

        // ---- delta_pos: 384 floats = 96 coalesced f4 nt stores ----
        __syncthreads();
        if (t < 96) {
            f4 dv = *(const f4*)&dl[t*4];
            __builtin_nontemporal_store(dv, (f4*)(out_delta) + (size_t)bid*96 + t);
        }
    }
}

extern "C" void kernel_launch(void* const* d_in, const int* in_sizes, int n_in,
                              void* d_out, int out_size, void* d_ws, size_t ws_size,
                              hipStream_t stream) {
    const float* coord     = (const float*)d_in[0];
    const float* atom_feat = (const float*)d_in[1];
    const int*   etype     = (const int*)  d_in[2];
    const float* edge_feat = (const float*)d_in[3];
    const float* mul_w     = (const float*)d_in[4];
    const float* bias_w    = (const float*)d_in[5];
    const float* mean      = (const float*)d_in[6];
    const float* w1        = (const float*)d_in[7];
    const float* b1        = (const float*)d_in[8];
    const float* w2        = (const float*)d_in[9];
    const float* b2        = (const float*)d_in[10];
    const float* ep_w      = (const float*)d_in[11];
    const float* ep_b      = (const float*)d_in[12];

    float* out = (float*)d_out;
    float* out_atom  = out;
    float* out_attn  = out + (size_t)NCg*NAg*EDIM;
    float* out_delta = out + (size_t)NCg*NAg*EDIM + (size_t)NEDGE*PDIM;

    auto tblBytes = [](int res){ return (size_t)(TSPAN*res+1)*PDIM*4; };
    int res;
    if      (ws_size >= tblBytes(16)) res = 16;   // 590 KB
    else if (ws_size >= tblBytes(4))  res = 4;
    else                              res = 1;
    int npt = TSPAN*res + 1;
    float* Tbl = (float*)d_ws;

    table_kernel<<<(npt + TPTS - 1)/TPTS, 128, 0, stream>>>(
        mean, w1, b1, w2, b2, Tbl, 1.0f/(float)res, npt);

    fused_kernel<<<NATOMBLK + NATTNBLK, 256, 0, stream>>>(
        coord, atom_feat, etype, mul_w, bias_w, mean, ep_w, ep_b,
        edge_feat, Tbl, (float)res, npt, out_atom, out_attn, out_delta);
}

// Round 9
// 80.186 us; speedup vs baseline: 1.6659x; 1.1516x over previous
//
#include <hip/hip_runtime.h>
#include <math.h>

typedef float f4 __attribute__((ext_vector_type(4)));

#define NCg 128
#define NAg 65
#define KNUM 128
#define PDIM 64
#define EDIM 256
#define NEDGE (NCg*NAg*NAg)      // 540800
#define NROWS (NCg*NAg)          // 8320
#define NATOMBLK (NROWS/16)      // 520 atom blocks
#define NATTNBLK (NEDGE/128)     // 4225 attn blocks
#define TLO -8.0f
#define TSPAN 144                // xs domain [-8,136]; clamped outside
#define TPTS 4                   // table grid points per block

// ---------------------------------------------------------------------------
// Kernel A: build g_d(xs) table.  (round-4 version — verified fast)
// ---------------------------------------------------------------------------
__launch_bounds__(128)
__global__ void table_kernel(const float* __restrict__ mean,
                             const float* __restrict__ w1,
                             const float* __restrict__ b1,
                             const float* __restrict__ w2,
                             const float* __restrict__ b2,
                             float* __restrict__ T,
                             float invres, int npt)
{
    __shared__ f4 wbuf[128*17];          // 34.8KB; w1 half [128 rows][16+1 f4]
                                         // reused for w2 as [64 rows][32+1 f4]
    __shared__ f4 gb4[KNUM];
    __shared__ f4 h4[KNUM];

    const int t  = threadIdx.x;          // 128 threads
    const int p0 = blockIdx.x * TPTS;

    const float stdv     = mean[1] - mean[0];
    const float inv_astd = 1.0f / (sqrtf(6.28318f) * stdv);

    {
        f4 g;
        float u0 = TLO + (float)(p0+0)*invres - (float)t;
        float u1 = TLO + (float)(p0+1)*invres - (float)t;
        float u2 = TLO + (float)(p0+2)*invres - (float)t;
        float u3 = TLO + (float)(p0+3)*invres - (float)t;
        g.x = expf(-0.5f*u0*u0) * inv_astd;
        g.y = expf(-0.5f*u1*u1) * inv_astd;
        g.z = expf(-0.5f*u2*u2) * inv_astd;
        g.w = expf(-0.5f*u3*u3) * inv_astd;
        gb4[t] = g;
    }

    f4 acc = {0.f, 0.f, 0.f, 0.f};
    for (int H = 0; H < 2; ++H) {
        __syncthreads();
        for (int it = 0; it < 16; ++it) {
            int u   = t + 128*it;
            int row = u >> 4;
            int c4  = u & 15;
            wbuf[row*17 + c4] = ((const f4*)w1)[row*32 + H*16 + c4];
        }
        __syncthreads();
        const f4* wr = &wbuf[t*17];
        #pragma unroll
        for (int kq = 0; kq < 16; ++kq) {
            f4 wv = wr[kq];
            int kb = H*64 + kq*4;
            acc = acc + wv.x * gb4[kb+0];
            acc = acc + wv.y * gb4[kb+1];
            acc = acc + wv.z * gb4[kb+2];
            acc = acc + wv.w * gb4[kb+3];
        }
    }
    {
        float b1t = b1[t];
        f4 hv;
        hv.x = 0.5f*acc.x*(1.0f + erff(acc.x*0.70710678118654752f)) + b1t;
        hv.y = 0.5f*acc.y*(1.0f + erff(acc.y*0.70710678118654752f)) + b1t;
        hv.z = 0.5f*acc.z*(1.0f + erff(acc.z*0.70710678118654752f)) + b1t;
        hv.w = 0.5f*acc.w*(1.0f + erff(acc.w*0.70710678118654752f)) + b1t;
        h4[t] = hv;
    }
    __syncthreads();
    for (int it = 0; it < 16; ++it) {
        int u   = t + 128*it;
        int row = u >> 5;
        int c4  = u & 31;
        wbuf[row*33 + c4] = ((const f4*)w2)[u];
    }
    __syncthreads();

    if (t < PDIM) {
        float b2t = b2[t];
        f4 o = {b2t, b2t, b2t, b2t};
        const f4* wr = &wbuf[t*33];
        #pragma unroll
        for (int kq = 0; kq < 32; ++kq) {
            f4 wv = wr[kq];
            o = o + wv.x * h4[kq*4+0];
            o = o + wv.y * h4[kq*4+1];
            o = o + wv.z * h4[kq*4+2];
            o = o + wv.w * h4[kq*4+3];
        }
        if (p0+0 < npt) T[(size_t)(p0+0)*PDIM + t] = o.x;
        if (p0+1 < npt) T[(size_t)(p0+1)*PDIM + t] = o.y;
        if (p0+2 < npt) T[(size_t)(p0+2)*PDIM + t] = o.z;
        if (p0+3 < npt) T[(size_t)(p0+3)*PDIM + t] = o.w;
    }
}

// ---------------------------------------------------------------------------
// Fused kernel: blocks [0, NATOMBLK) = atom path (round-4 form), rest = attn.
// attn v9: meta deduplicated WITHIN the wave (barrier-free).  Each wave owns
// 32 of the block's 128 edges; lanes 0-31 compute ONE edge's meta each
// (11 loads, ~45 VALU) + delta write; consumers pull idx/fr via __shfl
// (ds_bpermute, no barrier).  Replaces the 16x-redundant meta: 88 divergent
// loads + ~320 VALU per thread -> ~11 loads/wave + 16 shuffles/thread.
// Counters said latency/issue-bound (VALU 43%, HBM 26%, occ 30%), and meta
// was the dominant instruction-issue consumer.
// ---------------------------------------------------------------------------
__launch_bounds__(256)
__global__ void fused_kernel(const float* __restrict__ coord,
                             const float* __restrict__ atom_feat,
                             const int*   __restrict__ etype,
                             const float* __restrict__ mul_w,
                             const float* __restrict__ bias_w,
                             const float* __restrict__ mean,
                             const float* __restrict__ ep_w,
                             const float* __restrict__ ep_b,
                             const float* __restrict__ edge_feat,
                             const float* __restrict__ T,
                             float fres, int npt,
                             float* __restrict__ out_atom,
                             float* __restrict__ out_attn,
                             float* __restrict__ out_delta)
{
    __shared__ __attribute__((aligned(16))) float smem[16*NAg + 16*KNUM];

    const int t = threadIdx.x;
    const float stdv    = mean[1] - mean[0];
    const float inv_std = 1.0f / stdv;

    if (blockIdx.x < NATOMBLK) {
        // =================== atom path (exact round-4 body) ===================
        float* x_s   = smem;               // [16*NAg]
        float* sum_s = smem + 16*NAg;      // [16*KNUM]
        const int r0 = blockIdx.x * 16;
        const float inv_astd = 1.0f / (sqrtf(6.28318f) * stdv);

        for (int it = 0; it < 5; ++it) {
            int item = t + 256*it;
            if (item < 16*NAg) {
                int rr = item / NAg;
                int j  = item - rr*NAg;
                int r  = r0 + rr;
                int c  = r / NAg;
                int i  = r - c*NAg;
                const float* ci = coord + (c*NAg + i)*3;
                const float* cj = coord + (c*NAg + j)*3;
                float dx = cj[0]-ci[0], dy = cj[1]-ci[1], dz = cj[2]-ci[2];
                float dist = sqrtf(dx*dx + dy*dy + dz*dz);
                int t0 = etype[(r*NAg+j)*2+0], t1 = etype[(r*NAg+j)*2+1];
                float mul  = fabsf(mul_w[t0]) + fabsf(mul_w[t1]);
                float bias = bias_w[t0] + bias_w[t1];
                x_s[item] = (mul*dist + bias) * inv_std;
            }
        }
        __syncthreads();

        for (int it = 0; it < 8; ++it) {
            int item = t + 256*it;              // 16*128 = 2048
            int rr = item >> 7;
            int k  = item & 127;
            float fk = (float)k;
            const float* xr = &x_s[rr*NAg];
            float a0=0.f, a1=0.f, a2=0.f, a3=0.f;
            int j = 0;
            for (; j <= NAg-4; j += 4) {
                float u0 = xr[j+0]-fk, u1 = xr[j+1]-fk, u2 = xr[j+2]-fk, u3 = xr[j+3]-fk;
                a0 += exp2f(u0*u0 * -0.72134752f);
                a1 += exp2f(u1*u1 * -0.72134752f);
                a2 += exp2f(u2*u2 * -0.72134752f);
                a3 += exp2f(u3*u3 * -0.72134752f);
            }
            for (; j < NAg; ++j) {
                float u0 = xr[j]-fk;
                a0 += exp2f(u0*u0 * -0.72134752f);
            }
            sum_s[item] = ((a0+a1)+(a2+a3)) * inv_astd;
        }
        __syncthreads();

        {
            const int d = t;                    // 0..255
            float acc[16] = {};
            for (int kk = 0; kk < 32; ++kk) {
                f4 wv4 = *(const f4*)&ep_w[d*KNUM + 4*kk];
                #pragma unroll
                for (int rr = 0; rr < 16; ++rr) {
                    f4 sv = *(const f4*)&sum_s[rr*KNUM + 4*kk];
                    acc[rr] = fmaf(sv.x, wv4.x,
                              fmaf(sv.y, wv4.y,
                              fmaf(sv.z, wv4.z,
                              fmaf(sv.w, wv4.w, acc[rr]))));
                }
            }
            float epb = ep_b[d];
            #pragma unroll
            for (int rr = 0; rr < 16; ++rr) {
                int o = (r0 + rr)*EDIM + d;
                float af = __builtin_nontemporal_load(&atom_feat[o]);
                __builtin_nontemporal_store(af + acc[rr] + epb, &out_atom[o]);
            }
        }
    } else {
        // =================== attn path (wave-dedup meta) ===================
        float* dl = smem;                   // [128*3], 16B-aligned
        const int bid = blockIdx.x - NATOMBLK;
        const int w  = t >> 6;                        // wave 0..3
        const int l  = t & 63;                        // lane
        const int dq = t & 15;
        const int e  = (t >> 4) & 3;                  // er within wave
        const size_t u0 = (size_t)bid * 2048;         // f4 units
        const int e0 = bid * 128;

        // ---- edge_feature loads first: longest-latency, fully independent --
        f4 ef[8];
        #pragma unroll
        for (int p = 0; p < 8; ++p)
            ef[p] = ((const f4*)edge_feat)[u0 + p*256 + t];

        // ---- meta: lanes 0-31 compute ONE edge each (wave's 32 edges) ----
        int   m_idx = 0;
        float m_fr  = 0.0f;
        if (l < 32) {
            const int p  = l >> 2;
            const int ee = l & 3;
            const int el = p*16 + 4*w + ee;           // edge-local 0..127
            const int eg = e0 + el;
            int c   = eg / (NAg*NAg);
            int rem = eg - c*(NAg*NAg);
            int i   = rem / NAg;
            int j   = rem - i*NAg;
            const float* ci = coord + (c*NAg + i)*3;
            const float* cj = coord + (c*NAg + j)*3;
            float dx = cj[0]-ci[0], dy = cj[1]-ci[1], dz = cj[2]-ci[2];
            dl[el*3+0] = dx; dl[el*3+1] = dy; dl[el*3+2] = dz;
            float dist = sqrtf(dx*dx + dy*dy + dz*dz);
            int2 tp = *(const int2*)&etype[(size_t)eg*2];
            float mul  = fabsf(mul_w[tp.x]) + fabsf(mul_w[tp.y]);
            float bias = bias_w[tp.x] + bias_w[tp.y];
            float xs = (mul*dist + bias) * inv_std;
            float ti = (xs - TLO) * fres;
            int   ii = (int)ti;
            ii = ii < 0 ? 0 : (ii > npt-2 ? npt-2 : ii);
            float f = ti - (float)ii;
            m_fr  = f < 0.0f ? 0.0f : (f > 1.0f ? 1.0f : f);
            m_idx = ii;
        }

        // ---- per 4-edge group: shuffle idx/fr in, gather, lerp, nt store ----
        #pragma unroll
        for (int g = 0; g < 2; ++g) {
            f4 lo[4], hi[4]; float frq[4];
            #pragma unroll
            for (int q = 0; q < 4; ++q) {
                int p   = g*4 + q;
                int src = p*4 + e;                    // producer lane
                int ii  = __shfl(m_idx, src);
                frq[q]  = __shfl(m_fr, src);
                const float* tr = T + (size_t)ii*PDIM + dq*4;
                lo[q] = *(const f4*)tr;
                hi[q] = *(const f4*)(tr + PDIM);
            }
            #pragma unroll
            for (int q = 0; q < 4; ++q) {
                int p = g*4 + q;
                f4 o;
                o.x = fmaf(frq[q], hi[q].x - lo[q].x, lo[q].x) + ef[p].x;
                o.y = fmaf(frq[q], hi[q].y - lo[q].y, lo[q].y) + ef[p].y;
                o.z = fmaf(frq[q], hi[q].z - lo[q].z, lo[q].z) + ef[p].z;
                o.w = fmaf(frq[q], hi[q].w - lo[q].w, lo[q].w) + ef[p].w;
                __builtin_nontemporal_store(o, (f4*)out_attn + u0 + p*256 + t);
            }
        }

        // ---- delta_pos: 384 floats = 96 coalesced f4 nt stores ----
        __syncthreads();
        if (t < 96) {
            f4 dv = *(const f4*)&dl[t*4];
            __builtin_nontemporal_store(dv, (f4*)(out_delta) + (size_t)bid*96 + t);
        }
    }
}

extern "C" void kernel_launch(void* const* d_in, const int* in_sizes, int n_in,
                              void* d_out, int out_size, void* d_ws, size_t ws_size,
                              hipStream_t stream) {
    const float* coord     = (const float*)d_in[0];
    const float* atom_feat = (const float*)d_in[1];
    const int*   etype     = (const int*)  d_in[2];
    const float* edge_feat = (const float*)d_in[3];
    const float* mul_w     = (const float*)d_in[4];
    const float* bias_w    = (const float*)d_in[5];
    const float* mean      = (const float*)d_in[6];
    const float* w1        = (const float*)d_in[7];
    const float* b1        = (const float*)d_in[8];
    const float* w2        = (const float*)d_in[9];
    const float* b2        = (const float*)d_in[10];
    const float* ep_w      = (const float*)d_in[11];
    const float* ep_b      = (const float*)d_in[12];

    float* out = (float*)d_out;
    float* out_atom  = out;
    float* out_attn  = out + (size_t)NCg*NAg*EDIM;
    float* out_delta = out + (size_t)NCg*NAg*EDIM + (size_t)NEDGE*PDIM;

    auto tblBytes = [](int res){ return (size_t)(TSPAN*res+1)*PDIM*4; };
    int res;
    if      (ws_size >= tblBytes(16)) res = 16;   // 590 KB
    else if (ws_size >= tblBytes(4))  res = 4;
    else                              res = 1;
    int npt = TSPAN*res + 1;
    float* Tbl = (float*)d_ws;

    table_kernel<<<(npt + TPTS - 1)/TPTS, 128, 0, stream>>>(
        mean, w1, b1, w2, b2, Tbl, 1.0f/(float)res, npt);

    fused_kernel<<<NATOMBLK + NATTNBLK, 256, 0, stream>>>(
        coord, atom_feat, etype, mul_w, bias_w, mean, ep_w, ep_b,
        edge_feat, Tbl, (float)res, npt, out_atom, out_attn, out_delta);
}

// Round 10
// 78.623 us; speedup vs baseline: 1.6990x; 1.0199x over previous
//
#include <hip/hip_runtime.h>
#include <math.h>

typedef float f4 __attribute__((ext_vector_type(4)));

#define NCg 128
#define NAg 65
#define KNUM 128
#define PDIM 64
#define EDIM 256
#define NEDGE (NCg*NAg*NAg)      // 540800
#define NROWS (NCg*NAg)          // 8320
#define NATOMBLK (NROWS/16)      // 520 atom blocks
#define NATTNBLK (NEDGE/128)     // 4225 attn blocks
#define TLO -8.0f
#define TSPAN 144                // xs domain [-8,136]; clamped outside
#define TPTS 4                   // table grid points per block

// ---------------------------------------------------------------------------
// Kernel A: build g_d(xs) table.  (round-4 version — verified fast)
// ---------------------------------------------------------------------------
__launch_bounds__(128)
__global__ void table_kernel(const float* __restrict__ mean,
                             const float* __restrict__ w1,
                             const float* __restrict__ b1,
                             const float* __restrict__ w2,
                             const float* __restrict__ b2,
                             float* __restrict__ T,
                             float invres, int npt)
{
    __shared__ f4 wbuf[128*17];          // 34.8KB; w1 half [128 rows][16+1 f4]
                                         // reused for w2 as [64 rows][32+1 f4]
    __shared__ f4 gb4[KNUM];
    __shared__ f4 h4[KNUM];

    const int t  = threadIdx.x;          // 128 threads
    const int p0 = blockIdx.x * TPTS;

    const float stdv     = mean[1] - mean[0];
    const float inv_astd = 1.0f / (sqrtf(6.28318f) * stdv);

    {
        f4 g;
        float u0 = TLO + (float)(p0+0)*invres - (float)t;
        float u1 = TLO + (float)(p0+1)*invres - (float)t;
        float u2 = TLO + (float)(p0+2)*invres - (float)t;
        float u3 = TLO + (float)(p0+3)*invres - (float)t;
        g.x = expf(-0.5f*u0*u0) * inv_astd;
        g.y = expf(-0.5f*u1*u1) * inv_astd;
        g.z = expf(-0.5f*u2*u2) * inv_astd;
        g.w = expf(-0.5f*u3*u3) * inv_astd;
        gb4[t] = g;
    }

    f4 acc = {0.f, 0.f, 0.f, 0.f};
    for (int H = 0; H < 2; ++H) {
        __syncthreads();
        for (int it = 0; it < 16; ++it) {
            int u   = t + 128*it;
            int row = u >> 4;
            int c4  = u & 15;
            wbuf[row*17 + c4] = ((const f4*)w1)[row*32 + H*16 + c4];
        }
        __syncthreads();
        const f4* wr = &wbuf[t*17];
        #pragma unroll
        for (int kq = 0; kq < 16; ++kq) {
            f4 wv = wr[kq];
            int kb = H*64 + kq*4;
            acc = acc + wv.x * gb4[kb+0];
            acc = acc + wv.y * gb4[kb+1];
            acc = acc + wv.z * gb4[kb+2];
            acc = acc + wv.w * gb4[kb+3];
        }
    }
    {
        float b1t = b1[t];
        f4 hv;
        hv.x = 0.5f*acc.x*(1.0f + erff(acc.x*0.70710678118654752f)) + b1t;
        hv.y = 0.5f*acc.y*(1.0f + erff(acc.y*0.70710678118654752f)) + b1t;
        hv.z = 0.5f*acc.z*(1.0f + erff(acc.z*0.70710678118654752f)) + b1t;
        hv.w = 0.5f*acc.w*(1.0f + erff(acc.w*0.70710678118654752f)) + b1t;
        h4[t] = hv;
    }
    __syncthreads();
    for (int it = 0; it < 16; ++it) {
        int u   = t + 128*it;
        int row = u >> 5;
        int c4  = u & 31;
        wbuf[row*33 + c4] = ((const f4*)w2)[u];
    }
    __syncthreads();

    if (t < PDIM) {
        float b2t = b2[t];
        f4 o = {b2t, b2t, b2t, b2t};
        const f4* wr = &wbuf[t*33];
        #pragma unroll
        for (int kq = 0; kq < 32; ++kq) {
            f4 wv = wr[kq];
            o = o + wv.x * h4[kq*4+0];
            o = o + wv.y * h4[kq*4+1];
            o = o + wv.z * h4[kq*4+2];
            o = o + wv.w * h4[kq*4+3];
        }
        if (p0+0 < npt) T[(size_t)(p0+0)*PDIM + t] = o.x;
        if (p0+1 < npt) T[(size_t)(p0+1)*PDIM + t] = o.y;
        if (p0+2 < npt) T[(size_t)(p0+2)*PDIM + t] = o.z;
        if (p0+3 < npt) T[(size_t)(p0+3)*PDIM + t] = o.w;
    }
}

// ---------------------------------------------------------------------------
// Fused kernel: blocks [0, NATOMBLK) = atom path (round-4 form), rest = attn.
// attn v10 (scheduling only, numerics identical to v9):
//  (a) meta (etype+coord) loads issued FIRST — they head the longest dep
//      chain (etype -> xs -> shuffle -> T-gather -> store); ef loads issue
//      second and their latency hides under the meta chain.
//  (b) all 16 idx/fr shuffles batched before the gather loop -> 16 T-gathers
//      can be outstanding together.
//  (c) delta_pos stored DIRECTLY by producer lanes (3 nt dwords each,
//      48B-contiguous per 4-lane cluster) — removes the block barrier and
//      all attn LDS use; waves retire independently.
// ---------------------------------------------------------------------------
__launch_bounds__(256)
__global__ void fused_kernel(const float* __restrict__ coord,
                             const float* __restrict__ atom_feat,
                             const int*   __restrict__ etype,
                             const float* __restrict__ mul_w,
                             const float* __restrict__ bias_w,
                             const float* __restrict__ mean,
                             const float* __restrict__ ep_w,
                             const float* __restrict__ ep_b,
                             const float* __restrict__ edge_feat,
                             const float* __restrict__ T,
                             float fres, int npt,
                             float* __restrict__ out_atom,
                             float* __restrict__ out_attn,
                             float* __restrict__ out_delta)
{
    __shared__ __attribute__((aligned(16))) float smem[16*NAg + 16*KNUM];

    const int t = threadIdx.x;
    const float stdv    = mean[1] - mean[0];
    const float inv_std = 1.0f / stdv;

    if (blockIdx.x < NATOMBLK) {
        // =================== atom path (exact round-4 body) ===================
        float* x_s   = smem;               // [16*NAg]
        float* sum_s = smem + 16*NAg;      // [16*KNUM]
        const int r0 = blockIdx.x * 16;
        const float inv_astd = 1.0f / (sqrtf(6.28318f) * stdv);

        for (int it = 0; it < 5; ++it) {
            int item = t + 256*it;
            if (item < 16*NAg) {
                int rr = item / NAg;
                int j  = item - rr*NAg;
                int r  = r0 + rr;
                int c  = r / NAg;
                int i  = r - c*NAg;
                const float* ci = coord + (c*NAg + i)*3;
                const float* cj = coord + (c*NAg + j)*3;
                float dx = cj[0]-ci[0], dy = cj[1]-ci[1], dz = cj[2]-ci[2];
                float dist = sqrtf(dx*dx + dy*dy + dz*dz);
                int t0 = etype[(r*NAg+j)*2+0], t1 = etype[(r*NAg+j)*2+1];
                float mul  = fabsf(mul_w[t0]) + fabsf(mul_w[t1]);
                float bias = bias_w[t0] + bias_w[t1];
                x_s[item] = (mul*dist + bias) * inv_std;
            }
        }
        __syncthreads();

        for (int it = 0; it < 8; ++it) {
            int item = t + 256*it;              // 16*128 = 2048
            int rr = item >> 7;
            int k  = item & 127;
            float fk = (float)k;
            const float* xr = &x_s[rr*NAg];
            float a0=0.f, a1=0.f, a2=0.f, a3=0.f;
            int j = 0;
            for (; j <= NAg-4; j += 4) {
                float u0 = xr[j+0]-fk, u1 = xr[j+1]-fk, u2 = xr[j+2]-fk, u3 = xr[j+3]-fk;
                a0 += exp2f(u0*u0 * -0.72134752f);
                a1 += exp2f(u1*u1 * -0.72134752f);
                a2 += exp2f(u2*u2 * -0.72134752f);
                a3 += exp2f(u3*u3 * -0.72134752f);
            }
            for (; j < NAg; ++j) {
                float u0 = xr[j]-fk;
                a0 += exp2f(u0*u0 * -0.72134752f);
            }
            sum_s[item] = ((a0+a1)+(a2+a3)) * inv_astd;
        }
        __syncthreads();

        {
            const int d = t;                    // 0..255
            float acc[16] = {};
            for (int kk = 0; kk < 32; ++kk) {
                f4 wv4 = *(const f4*)&ep_w[d*KNUM + 4*kk];
                #pragma unroll
                for (int rr = 0; rr < 16; ++rr) {
                    f4 sv = *(const f4*)&sum_s[rr*KNUM + 4*kk];
                    acc[rr] = fmaf(sv.x, wv4.x,
                              fmaf(sv.y, wv4.y,
                              fmaf(sv.z, wv4.z,
                              fmaf(sv.w, wv4.w, acc[rr]))));
                }
            }
            float epb = ep_b[d];
            #pragma unroll
            for (int rr = 0; rr < 16; ++rr) {
                int o = (r0 + rr)*EDIM + d;
                float af = __builtin_nontemporal_load(&atom_feat[o]);
                __builtin_nontemporal_store(af + acc[rr] + epb, &out_atom[o]);
            }
        }
    } else {
        // =================== attn path (wave-dedup meta, v10) ===============
        const int bid = blockIdx.x - NATOMBLK;
        const int w  = t >> 6;                        // wave 0..3
        const int l  = t & 63;                        // lane
        const int dq = t & 15;
        const int e  = (t >> 4) & 3;                  // er within wave
        const size_t u0 = (size_t)bid * 2048;         // f4 units
        const int e0 = bid * 128;

        // ---- (a) meta FIRST: lanes 0-31 compute ONE edge each ----
        int   m_idx = 0;
        float m_fr  = 0.0f;
        if (l < 32) {
            const int p  = l >> 2;
            const int ee = l & 3;
            const int el = p*16 + 4*w + ee;           // edge-local 0..127
            const int eg = e0 + el;
            int c   = eg / (NAg*NAg);
            int rem = eg - c*(NAg*NAg);
            int i   = rem / NAg;
            int j   = rem - i*NAg;
            const float* ci = coord + (c*NAg + i)*3;
            const float* cj = coord + (c*NAg + j)*3;
            float dx = cj[0]-ci[0], dy = cj[1]-ci[1], dz = cj[2]-ci[2];
            // (c) delta direct from producer registers (48B per 4-lane cluster)
            float* dp = out_delta + (size_t)(e0 + el)*3;
            __builtin_nontemporal_store(dx, dp+0);
            __builtin_nontemporal_store(dy, dp+1);
            __builtin_nontemporal_store(dz, dp+2);
            float dist = sqrtf(dx*dx + dy*dy + dz*dz);
            int2 tp = *(const int2*)&etype[(size_t)eg*2];
            float mul  = fabsf(mul_w[tp.x]) + fabsf(mul_w[tp.y]);
            float bias = bias_w[tp.x] + bias_w[tp.y];
            float xs = (mul*dist + bias) * inv_std;
            float ti = (xs - TLO) * fres;
            int   ii = (int)ti;
            ii = ii < 0 ? 0 : (ii > npt-2 ? npt-2 : ii);
            float f = ti - (float)ii;
            m_fr  = f < 0.0f ? 0.0f : (f > 1.0f ? 1.0f : f);
            m_idx = ii;
        }

        // ---- ef loads second: independent; latency hides under meta chain --
        f4 ef[8];
        #pragma unroll
        for (int p = 0; p < 8; ++p)
            ef[p] = ((const f4*)edge_feat)[u0 + p*256 + t];

        // ---- (b) all shuffles batched ----
        int idx[8]; float fr[8];
        #pragma unroll
        for (int p = 0; p < 8; ++p) {
            int src = p*4 + e;                        // producer lane
            idx[p] = __shfl(m_idx, src);
            fr[p]  = __shfl(m_fr, src);
        }

        // ---- per 4-edge group: gather + lerp + add + nt store ----
        #pragma unroll
        for (int g = 0; g < 2; ++g) {
            f4 lo[4], hi[4];
            #pragma unroll
            for (int q = 0; q < 4; ++q) {
                int p = g*4 + q;
                const float* tr = T + (size_t)idx[p]*PDIM + dq*4;
                lo[q] = *(const f4*)tr;
                hi[q] = *(const f4*)(tr + PDIM);
            }
            #pragma unroll
            for (int q = 0; q < 4; ++q) {
                int p = g*4 + q;
                f4 o;
                o.x = fmaf(fr[p], hi[q].x - lo[q].x, lo[q].x) + ef[p].x;
                o.y = fmaf(fr[p], hi[q].y - lo[q].y, lo[q].y) + ef[p].y;
                o.z = fmaf(fr[p], hi[q].z - lo[q].z, lo[q].z) + ef[p].z;
                o.w = fmaf(fr[p], hi[q].w - lo[q].w, lo[q].w) + ef[p].w;
                __builtin_nontemporal_store(o, (f4*)out_attn + u0 + p*256 + t);
            }
        }
    }
}

extern "C" void kernel_launch(void* const* d_in, const int* in_sizes, int n_in,
                              void* d_out, int out_size, void* d_ws, size_t ws_size,
                              hipStream_t stream) {
    const float* coord     = (const float*)d_in[0];
    const float* atom_feat = (const float*)d_in[1];
    const int*   etype     = (const int*)  d_in[2];
    const float* edge_feat = (const float*)d_in[3];
    const float* mul_w     = (const float*)d_in[4];
    const float* bias_w    = (const float*)d_in[5];
    const float* mean      = (const float*)d_in[6];
    const float* w1        = (const float*)d_in[7];
    const float* b1        = (const float*)d_in[8];
    const float* w2        = (const float*)d_in[9];
    const float* b2        = (const float*)d_in[10];
    const float* ep_w      = (const float*)d_in[11];
    const float* ep_b      = (const float*)d_in[12];

    float* out = (float*)d_out;
    float* out_atom  = out;
    float* out_attn  = out + (size_t)NCg*NAg*EDIM;
    float* out_delta = out + (size_t)NCg*NAg*EDIM + (size_t)NEDGE*PDIM;

    auto tblBytes = [](int res){ return (size_t)(TSPAN*res+1)*PDIM*4; };
    int res;
    if      (ws_size >= tblBytes(16)) res = 16;   // 590 KB
    else if (ws_size >= tblBytes(4))  res = 4;
    else                              res = 1;
    int npt = TSPAN*res + 1;
    float* Tbl = (float*)d_ws;

    table_kernel<<<(npt + TPTS - 1)/TPTS, 128, 0, stream>>>(
        mean, w1, b1, w2, b2, Tbl, 1.0f/(float)res, npt);

    fused_kernel<<<NATOMBLK + NATTNBLK, 256, 0, stream>>>(
        coord, atom_feat, etype, mul_w, bias_w, mean, ep_w, ep_b,
        edge_feat, Tbl, (float)res, npt, out_atom, out_attn, out_delta);
}